// Round 1
// baseline (295.894 us; speedup 1.0000x reference)
//
#include <hip/hip_runtime.h>

// TriadicClosureModule: the reference computes
//   g = -sum((E - E)^2) == 0 exactly (elementwise zero),
//   w = C * g == +/-0.0 (C is finite: denom clamped to 1e-6),
//   lambda_tri = mask @ w == +/-0.0 for every pair.
// So the output is exactly the zero vector of length P. The only required
// work is zero-filling d_out (harness re-poisons it to 0xAA before every
// timed launch, so the write must happen each call).

__global__ void triadic_zero_out(float4* __restrict__ out, int n4) {
    int i = blockIdx.x * blockDim.x + threadIdx.x;
    if (i < n4) out[i] = make_float4(0.0f, 0.0f, 0.0f, 0.0f);
}

__global__ void triadic_zero_tail(float* __restrict__ out, int start, int n) {
    int i = start + blockIdx.x * blockDim.x + threadIdx.x;
    if (i < n) out[i] = 0.0f;
}

extern "C" void kernel_launch(void* const* d_in, const int* in_sizes, int n_in,
                              void* d_out, int out_size, void* d_ws, size_t ws_size,
                              hipStream_t stream) {
    float* out = (float*)d_out;
    int n = out_size;            // P = 16384
    int n4 = n / 4;              // vectorized float4 stores (16 B/lane)
    if (n4 > 0) {
        int threads = 256;
        int blocks = (n4 + threads - 1) / threads;
        triadic_zero_out<<<blocks, threads, 0, stream>>>((float4*)out, n4);
    }
    int tail_start = n4 * 4;
    int tail = n - tail_start;
    if (tail > 0) {
        triadic_zero_tail<<<1, 64, 0, stream>>>(out, tail_start, n);
    }
}